// Round 11
// baseline (229.361 us; speedup 1.0000x reference)
//
#include <hip/hip_runtime.h>
#include <hip/hip_bf16.h>
#include <stdint.h>
#include <math.h>

#define BB 4
#define NN 2048
#define NFEAT 256
#define NHID 64
#define NHEADS 4
#define NCLASS 32
#define KK1 256
#define ALPHA 0.2f
#define LOG2E 1.4426950408889634f

#define PROJ_BLOCKS (BB*NHEADS*(NN/64))   // 512

typedef _Float16 f16x8 __attribute__((ext_vector_type(8)));
typedef _Float16 f16x4 __attribute__((ext_vector_type(4)));
typedef _Float16 h16x2 __attribute__((ext_vector_type(2)));
typedef float f32x4 __attribute__((ext_vector_type(4)));

__device__ __forceinline__ f16x8 ld8(const _Float16* p){
  f16x8 r;
  *(f16x4*)&r = *(const f16x4*)p;
  *((f16x4*)&r + 1) = *(const f16x4*)(p + 4);
  return r;
}

__device__ __forceinline__ h16x2 pk2(float a, float b){
  auto v = __builtin_amdgcn_cvt_pkrtz(a, b);   // __fp16 x2
  h16x2 r;
  __builtin_memcpy(&r, &v, sizeof(r));
  return r;
}

__device__ __forceinline__ float fexp2(float x){
#if __has_builtin(__builtin_amdgcn_exp2f)
  return __builtin_amdgcn_exp2f(x);
#else
  return exp2f(x);
#endif
}

// spread bits 0..15 of y to positions 0,4,8,...,60 (4-stride expand)
__device__ __forceinline__ unsigned long long expand4(unsigned long long y){
  y &= 0xFFFFull;
  y = (y | (y << 24)) & 0x000000FF000000FFull;
  y = (y | (y << 12)) & 0x000F000F000F000Full;
  y = (y | (y << 6))  & 0x0303030303030303ull;
  y = (y | (y << 3))  & 0x1111111111111111ull;
  return y;
}

// ---------------- K0+K1 merged: pack_adj || wh_proj2 --------------------
// v12: (a) pack half = ONE int4 load round-trip per row (was 4 dependent
// load->ballot rounds); 4 ballots + wave-uniform SALU bit-interleave
// reassemble the identical ull layout (bit k of word wv*4+m comes from
// lane 16m+k/4, component k%4). (b) proj half: xs PITCH 66 + float2
// ds_read_b64 (2-way bank aliasing = free), halves LDS issue count.
// Both transforms bit-exact. W addressing stays wave-uniform (v10 lesson:
// per-lane dbase kills the scalar-load path).
__global__ void __launch_bounds__(512) prep(const float* __restrict__ x,
        const float* __restrict__ W, const float* __restrict__ a1, const float* __restrict__ a2,
        _Float16* __restrict__ whT, float* __restrict__ f1l, float* __restrict__ f2l,
        const int* __restrict__ adj, unsigned long long* __restrict__ bits,
        int* __restrict__ cnt){
  __shared__ __align__(16) float xs[64*66];     // 16.9 KB
  __shared__ float red1[8][64];
  __shared__ float red2[8][64];
  __shared__ int csum[8];
  int tid = threadIdx.x;
  int lane = tid & 63, wv = tid >> 6;           // wv 0..7
  if (blockIdx.x >= PROJ_BLOCKS){
    // ---- pack_adj: one row per block, single int4 sweep ----
    int row = blockIdx.x - PROJ_BLOCKS;         // b*N + i
    const int4* arow = (const int4*)(adj + (size_t)row * NN);
    int4 v = arow[tid];                         // ints [4*tid, 4*tid+4)
    unsigned long long bx = __ballot(v.x > 0);  // wave-uniform
    unsigned long long by = __ballot(v.y > 0);
    unsigned long long bz = __ballot(v.z > 0);
    unsigned long long bw = __ballot(v.w > 0);
    if (lane == 0){
      unsigned long long* bdst = bits + (size_t)row*(NN/64) + wv*4;
      #pragma unroll
      for (int m=0; m<4; ++m){
        unsigned long long w64 =  expand4(bx >> (16*m))
                               | (expand4(by >> (16*m)) << 1)
                               | (expand4(bz >> (16*m)) << 2)
                               | (expand4(bw >> (16*m)) << 3);
        bdst[m] = w64;
      }
      csum[wv] = (int)(__popcll(bx) + __popcll(by) + __popcll(bz) + __popcll(bw));
    }
    __syncthreads();
    if (tid==0){
      int s = 0;
      #pragma unroll
      for (int g=0; g<8; ++g) s += csum[g];
      cnt[row] = s;
    }
    return;
  }
  // ---- wh_proj2 part: 64-row tile, 8 waves x 8 wave-uniform cols ----
  int bh = blockIdx.x >> 5;
  int i0 = (blockIdx.x & 31) * 64;
  int b = bh >> 2, h = bh & 3;
  int dbase = __builtin_amdgcn_readfirstlane(tid >> 6) * 8;   // wave-uniform
  int row_s = tid >> 3;                         // staging row 0..63
  int f8 = (tid & 7) * 8;                       // staging f offset
  float2 acc2[4];
  #pragma unroll
  for (int dd=0; dd<4; ++dd) acc2[dd] = float2{0.f, 0.f};
  for (int kc=0; kc<4; ++kc){
    int kb = kc*64;
    __syncthreads();
    {
      const float* xp = x + ((size_t)(b*NN + i0 + row_s))*NFEAT + kb + f8;
      float4 v0 = *(const float4*)(xp);
      float4 v1 = *(const float4*)(xp + 4);
      float* xd = &xs[row_s*66 + f8];
      xd[0]=v0.x; xd[1]=v0.y; xd[2]=v0.z; xd[3]=v0.w;
      xd[4]=v1.x; xd[5]=v1.y; xd[6]=v1.z; xd[7]=v1.w;
    }
    __syncthreads();
    const float* Wb = W + (size_t)h*NFEAT*NHID + (size_t)kb*NHID + dbase;
    #pragma unroll 4
    for (int f2=0; f2<32; ++f2){
      float2 xv = *(const float2*)&xs[lane*66 + f2*2];
      const float2* wrA = (const float2*)(Wb + (size_t)(f2*2)*NHID);
      const float2* wrB = (const float2*)(Wb + (size_t)(f2*2+1)*NHID);
      #pragma unroll
      for (int dd=0; dd<4; ++dd){
        acc2[dd].x = fmaf(xv.x, wrA[dd].x, acc2[dd].x);
        acc2[dd].y = fmaf(xv.x, wrA[dd].y, acc2[dd].y);
      }
      #pragma unroll
      for (int dd=0; dd<4; ++dd){
        acc2[dd].x = fmaf(xv.y, wrB[dd].x, acc2[dd].x);
        acc2[dd].y = fmaf(xv.y, wrB[dd].y, acc2[dd].y);
      }
    }
  }
  float p1 = 0.f, p2 = 0.f;
  #pragma unroll
  for (int dd=0; dd<8; ++dd){
    int d = dbase + dd;
    float a = (dd & 1) ? acc2[dd>>1].y : acc2[dd>>1].x;
    whT[((size_t)bh*NHID + d)*NN + i0 + lane] = (_Float16)a;
    p1 = fmaf(a, a1[h*NHID + d], p1);
    p2 = fmaf(a, a2[h*NHID + d], p2);
  }
  red1[wv][lane] = p1;
  red2[wv][lane] = p2;
  __syncthreads();
  if (tid < 64){
    float s1 = 0.f, s2 = 0.f;
    #pragma unroll
    for (int g=0; g<8; ++g){ s1 += red1[g][tid]; s2 += red2[g][tid]; }
    f1l[(size_t)bh*NN + i0 + tid] = s1 * LOG2E;
    f2l[(size_t)bh*NN + i0 + tid] = s2 * LOG2E;
  }
}

// ---------- K2: partial softmax(e) @ Wh, j-split x2, f16 MFMA -----------
// v7 structure (measured <40.2us): T14 async-STAGE register prefetch,
// exp2-in-loop weight path, AND-mask after exp2, grid 2048.
__global__ void __launch_bounds__(256) attn_l1(
        const unsigned long long* __restrict__ bits,
        const _Float16* __restrict__ whT,
        const float* __restrict__ f1l, const float* __restrict__ f2l,
        const int* __restrict__ cnt_in,
        float* __restrict__ pc, float* __restrict__ pl){
  const int JC = 128, PITCH = 132;
  __shared__ __align__(16) _Float16 whs[64*PITCH];   // 16.9 KB
  __shared__ __align__(16) _Float16 wts[32*PITCH];   // 8.4 KB
  int blk = blockIdx.x;
  int js = blk & 1;
  int tile = (blk >> 1) & 63;
  int bh = blk >> 7;
  int b = bh >> 2, h = bh & 3;
  int i0 = tile*32;
  int tid = threadIdx.x;
  int lane = tid & 63, wv = tid >> 6;
  int q = lane >> 4, col = lane & 15;
  int r = tid >> 3, jg = (tid & 7) * 16;
  float f1r = f1l[(size_t)bh*NN + i0 + r];
  bool czr = (cnt_in[b*NN + i0 + r] == 0);
  const unsigned short* mrow = (const unsigned short*)(bits + ((size_t)(b*NN + i0 + r))*(NN/64));
  const float* f2p = f2l + (size_t)bh*NN;
  const _Float16* whg = whT + (size_t)bh*NHID*NN;
  float lacc = 0.f;
  f32x4 c0 = {0.f,0.f,0.f,0.f}, c1 = {0.f,0.f,0.f,0.f};

  // register staging state (one j-chunk ahead)
  int sd0 = tid >> 4;            // staging row base (+16*dd)
  int sj8 = (tid & 15) * 8;      // staging j offset
  uint4 sreg[4];
  auto issue = [&](int it){
    #pragma unroll
    for (int dd=0; dd<4; ++dd)
      sreg[dd] = *(const uint4*)(whg + (size_t)(sd0 + dd*16)*NN + it*JC + sj8);
  };
  auto commit = [&](){
    #pragma unroll
    for (int dd=0; dd<4; ++dd){
      uint2* w2 = (uint2*)&whs[(sd0 + dd*16)*PITCH + sj8];
      w2[0] = uint2{sreg[dd].x, sreg[dd].y};
      w2[1] = uint2{sreg[dd].z, sreg[dd].w};
    }
  };

  issue(js*8);                   // prologue: first chunk (latency exposed once)
  for (int ii=0; ii<8; ++ii){
    int it = js*8 + ii;
    __syncthreads();             // whs free to overwrite
    commit();                    // ds_write from regs loaded last iter
    if (ii < 7) issue(it+1);     // prefetch next chunk; covered by rest of iter
    // weights: 32 rows x 128 j; 8 threads/row, 16 j each
    {
      unsigned int m16 = mrow[it*8 + (tid&7)];
      const float* fp = f2p + it*JC + jg;
      float4 fa = *(const float4*)(fp);
      float4 fb = *(const float4*)(fp+4);
      float4 fc = *(const float4*)(fp+8);
      float4 fd = *(const float4*)(fp+12);
      float fv[16] = {fa.x,fa.y,fa.z,fa.w, fb.x,fb.y,fb.z,fb.w,
                      fc.x,fc.y,fc.z,fc.w, fd.x,fd.y,fd.z,fd.w};
      h16x2 wp[8];
      #pragma unroll
      for (int p=0; p<8; ++p){
        float s0 = f1r + fv[2*p];
        float s1 = f1r + fv[2*p+1];
        float w0 = fexp2(fmaxf(s0, ALPHA*s0));
        float w1 = fexp2(fmaxf(s1, ALPHA*s1));
        // mask after exp2: masked lanes -> +0.0 (identical to exp2(-big))
        unsigned mb0 = (unsigned)(((int)(m16 << (31 - 2*p))) >> 31);
        unsigned mb1 = (unsigned)(((int)(m16 << (30 - 2*p))) >> 31);
        w0 = __uint_as_float(__float_as_uint(w0) & mb0);
        w1 = __uint_as_float(__float_as_uint(w1) & mb1);
        lacc += w0 + w1;
        wp[p] = pk2(w0, w1);
      }
      if (__builtin_expect(czr, 0)){
        h16x2 one2 = {(_Float16)1.f, (_Float16)1.f};
        #pragma unroll
        for (int p=0; p<8; ++p) wp[p] = one2;
      }
      uint2* wdst = (uint2*)&wts[r*PITCH + jg];
      const uint2* wsrc = (const uint2*)&wp[0];
      wdst[0]=wsrc[0]; wdst[1]=wsrc[1]; wdst[2]=wsrc[2]; wdst[3]=wsrc[3];
    }
    __syncthreads();
    // MFMA: wave wv = n-tile, 2 m-tiles, 4 k-steps
    #pragma unroll
    for (int ks=0; ks<4; ++ks){
      int kb = ks*32 + q*8;
      f16x8 a0 = ld8(&wts[col*PITCH + kb]);
      f16x8 a1v = ld8(&wts[(16+col)*PITCH + kb]);
      f16x8 bv = ld8(&whs[(wv*16+col)*PITCH + kb]);
      c0 = __builtin_amdgcn_mfma_f32_16x16x32_f16(a0, bv, c0, 0, 0, 0);
      c1 = __builtin_amdgcn_mfma_f32_16x16x32_f16(a1v, bv, c1, 0, 0, 0);
    }
  }
  lacc += __shfl_xor(lacc, 1, 64);
  lacc += __shfl_xor(lacc, 2, 64);
  lacc += __shfl_xor(lacc, 4, 64);
  float* plh = pl + (size_t)js*BB*NHEADS*NN;
  if ((tid & 7) == 0) plh[(size_t)bh*NN + i0 + r] = czr ? (float)(NN/2) : lacc;
  float* pch = pc + (size_t)js*BB*NN*(NHEADS*NHID);
  int dloc = wv*16 + col;
  #pragma unroll
  for (int mt=0; mt<2; ++mt){
    #pragma unroll
    for (int reg=0; reg<4; ++reg){
      int ir = mt*16 + q*4 + reg;
      pch[((size_t)(b*NN + i0 + ir))*(NHEADS*NHID) + h*NHID + dloc] =
          (mt==0 ? c0[reg] : c1[reg]);
    }
  }
}

// ---------------- K3a: fused combine + Wh2T = (h1 @ Wo)^T ---------------
// v8: 32 rows/block -> 256 blocks. Per-output math identical to v7.
__global__ void __launch_bounds__(256) out_proj2(const float* __restrict__ pa,
        const float* __restrict__ pb, const float* __restrict__ la, const float* __restrict__ lb,
        const float* __restrict__ Wo, const float* __restrict__ ao1, const float* __restrict__ ao2,
        _Float16* __restrict__ whT2, float* __restrict__ f1ol, float* __restrict__ f2ol){
  __shared__ __align__(16) float xs[32*65];    // 8.3 KB
  __shared__ float red1[8][32];
  __shared__ float red2[8][32];
  int b  = blockIdx.x >> 6;
  int i0 = (blockIdx.x & 63) * 32;
  int tid = threadIdx.x;
  int lane = tid & 63;
  int row_c = lane & 31;                        // compute row
  int grp = ((tid >> 6) << 1) | (lane >> 5);    // 0..7 col group
  int dbase = grp * 4;
  int row_s = tid >> 3;                         // staging row
  int f8 = (tid & 7) * 8;
  float acc[4] = {0.f,0.f,0.f,0.f};
  for (int kc=0; kc<4; ++kc){
    int kb = kc*64;
    __syncthreads();
    {
      int i = i0 + row_s;
      size_t lidx = ((size_t)(b*NHEADS + kc))*NN + i;
      float il = 1.f / (la[lidx] + lb[lidx]);
      size_t idx = ((size_t)(b*NN + i))*256 + kb + f8;
      float4 va0 = *(const float4*)(pa + idx);
      float4 va1 = *(const float4*)(pa + idx + 4);
      float4 vb0 = *(const float4*)(pb + idx);
      float4 vb1 = *(const float4*)(pb + idx + 4);
      float v[8] = {va0.x+vb0.x, va0.y+vb0.y, va0.z+vb0.z, va0.w+vb0.w,
                    va1.x+vb1.x, va1.y+vb1.y, va1.z+vb1.z, va1.w+vb1.w};
      #pragma unroll
      for (int k=0; k<8; ++k){
        float t2 = v[k]*il;
        xs[row_s*65 + f8 + k] = t2 > 0.f ? t2 : expm1f(t2);
      }
    }
    __syncthreads();
    #pragma unroll 4
    for (int f=0; f<64; ++f){
      float xv = xs[row_c*65 + f];
      float4 w4 = *(const float4*)(Wo + (size_t)(kb+f)*NCLASS + dbase);
      acc[0] = fmaf(xv, w4.x, acc[0]);
      acc[1] = fmaf(xv, w4.y, acc[1]);
      acc[2] = fmaf(xv, w4.z, acc[2]);
      acc[3] = fmaf(xv, w4.w, acc[3]);
    }
  }
  float p1 = 0.f, p2 = 0.f;
  #pragma unroll
  for (int dd=0; dd<4; ++dd){
    int d = dbase + dd;
    whT2[((size_t)b*NCLASS + d)*NN + i0 + row_c] = (_Float16)acc[dd];
    p1 = fmaf(acc[dd], ao1[d], p1);
    p2 = fmaf(acc[dd], ao2[d], p2);
  }
  red1[grp][row_c] = p1;
  red2[grp][row_c] = p2;
  __syncthreads();
  if (tid < 32){
    float s1 = 0.f, s2 = 0.f;
    #pragma unroll
    for (int g=0; g<8; ++g){ s1 += red1[g][tid]; s2 += red2[g][tid]; }
    f1ol[(size_t)b*NN + i0 + tid] = s1 * LOG2E;
    f2ol[(size_t)b*NN + i0 + tid] = s2 * LOG2E;
  }
}

// ---------- K3b: layer-2 attention, GATHERED rows only, j-split x8 ------
__global__ void __launch_bounds__(256) attn_l2(
        const unsigned long long* __restrict__ bits,
        const _Float16* __restrict__ whT2,
        const float* __restrict__ f1ol, const float* __restrict__ f2ol,
        const int* __restrict__ cnt_in, const int* __restrict__ oh,
        float* __restrict__ pc, float* __restrict__ pl){
  const int JC = 128, PITCH = 132;
  __shared__ __align__(16) _Float16 whs[32*PITCH];
  __shared__ __align__(16) _Float16 wts[32*PITCH];
  int blk = blockIdx.x;
  int js = blk & 7, kt = (blk>>3) & 7, b = blk >> 6;
  int tid = threadIdx.x;
  int lane = tid & 63, wv = tid >> 6;
  int q = lane >> 4, col = lane & 15;
  int r = tid >> 3, jg = (tid & 7) * 16;
  int row_i = oh[b*KK1 + kt*32 + r];
  float f1r = f1ol[b*NN + row_i];
  bool czr = (cnt_in[b*NN + row_i] == 0);
  const unsigned short* mrow = (const unsigned short*)(bits + ((size_t)(b*NN + row_i))*(NN/64));
  const float* f2p = f2ol + (size_t)b*NN;
  const _Float16* whg = whT2 + (size_t)b*NCLASS*NN;
  float lacc = 0.f;
  f32x4 c0 = {0.f,0.f,0.f,0.f};
  int mt = wv & 1, nt = wv >> 1;
  for (int ii=0; ii<2; ++ii){
    int it = js*2 + ii;
    __syncthreads();
    #pragma unroll
    for (int dd=0; dd<2; ++dd){
      int d = (tid>>4) + dd*16;
      int j8 = (tid&15)*8;
      uint4 v = *(const uint4*)(whg + (size_t)d*NN + it*JC + j8);
      uint2* w2 = (uint2*)&whs[d*PITCH + j8];
      w2[0] = uint2{v.x, v.y};
      w2[1] = uint2{v.z, v.w};
    }
    {
      unsigned int m16 = mrow[it*8 + (tid&7)];
      const float* fp = f2p + it*JC + jg;
      float4 fa = *(const float4*)(fp);
      float4 fb = *(const float4*)(fp+4);
      float4 fc = *(const float4*)(fp+8);
      float4 fd = *(const float4*)(fp+12);
      float fv[16] = {fa.x,fa.y,fa.z,fa.w, fb.x,fb.y,fb.z,fb.w,
                      fc.x,fc.y,fc.z,fc.w, fd.x,fd.y,fd.z,fd.w};
      h16x2 wp[8];
      #pragma unroll
      for (int p=0; p<8; ++p){
        float s0 = f1r + fv[2*p];
        float s1 = f1r + fv[2*p+1];
        s0 = (m16 & (1u<<(2*p)))   ? s0 : -1e5f;
        s1 = (m16 & (1u<<(2*p+1))) ? s1 : -1e5f;
        float e0 = fmaxf(s0, ALPHA*s0);
        float e1 = fmaxf(s1, ALPHA*s1);
        float w0 = exp2f(e0);
        float w1 = exp2f(e1);
        lacc += w0 + w1;
        wp[p] = pk2(w0, w1);
      }
      if (__builtin_expect(czr, 0)){
        h16x2 one2 = {(_Float16)1.f, (_Float16)1.f};
        #pragma unroll
        for (int p=0; p<8; ++p) wp[p] = one2;
        lacc += 16.f;
      }
      uint2* wdst = (uint2*)&wts[r*PITCH + jg];
      const uint2* wsrc = (const uint2*)&wp[0];
      wdst[0]=wsrc[0]; wdst[1]=wsrc[1]; wdst[2]=wsrc[2]; wdst[3]=wsrc[3];
    }
    __syncthreads();
    #pragma unroll
    for (int ks=0; ks<4; ++ks){
      int kb = ks*32 + q*8;
      f16x8 a0 = ld8(&wts[(mt*16+col)*PITCH + kb]);
      f16x8 bv = ld8(&whs[(nt*16+col)*PITCH + kb]);
      c0 = __builtin_amdgcn_mfma_f32_16x16x32_f16(a0, bv, c0, 0, 0, 0);
    }
  }
  lacc += __shfl_xor(lacc, 1, 64);
  lacc += __shfl_xor(lacc, 2, 64);
  lacc += __shfl_xor(lacc, 4, 64);
  if ((tid & 7) == 0) pl[blk*32 + r] = lacc;
  int dloc = nt*16 + col;
  #pragma unroll
  for (int reg=0; reg<4; ++reg){
    int ir = mt*16 + q*4 + reg;
    pc[(size_t)blk*1024 + ir*32 + dloc] = c0[reg];
  }
}

// ---------------- K4: combine partials + ELU + MLP ----------------------
__global__ void __launch_bounds__(256) classify2(const float* __restrict__ pc,
        const float* __restrict__ pl,
        const float* __restrict__ W1, const float* __restrict__ b1,
        const float* __restrict__ pw, const float* __restrict__ W2, const float* __restrict__ b2,
        float* __restrict__ out){
  __shared__ float efs[4][32];
  int wv = threadIdx.x >> 6;
  int lane = threadIdx.x & 63;
  int row = blockIdx.x*4 + wv;        // 0..B*K1-1
  int b = row >> 8, k = row & 255;
  int kt = k >> 5, r = k & 31;
  int base = (b*8 + kt)*8;
  if (lane < 32){
    float s = 0.f, l = 0.f;
    #pragma unroll
    for (int js=0; js<8; ++js){
      s += pc[(size_t)(base+js)*1024 + r*32 + lane];
      l += pl[(base+js)*32 + r];
    }
    float v = s / l;
    v = v > 0.f ? v : expm1f(v);
    efs[wv][lane] = v;
  }
  __syncthreads();
  const float* ef = efs[wv];
  int c = lane & 31;
  float y = b1[c];
  #pragma unroll 8
  for (int kk=0; kk<32; ++kk) y += ef[kk] * W1[kk*32 + c];
  y = y > 0.f ? y : pw[c]*y;
  float o0 = y * W2[c*2+0];
  float o1 = y * W2[c*2+1];
  #pragma unroll
  for (int o=16;o>0;o>>=1){ o0 += __shfl_xor(o0,o,64); o1 += __shfl_xor(o1,o,64); }
  if (lane==0){ out[row*2+0] = o0 + b2[0]; out[row*2+1] = o1 + b2[1]; }
}

extern "C" void kernel_launch(void* const* d_in, const int* in_sizes, int n_in,
                              void* d_out, int out_size, void* d_ws, size_t ws_size,
                              hipStream_t stream) {
  const float* x    = (const float*)d_in[0];
  const int*   adj  = (const int*)  d_in[1];
  const int*   oh   = (const int*)  d_in[2];
  const float* W    = (const float*)d_in[3];
  const float* a1   = (const float*)d_in[4];
  const float* a2   = (const float*)d_in[5];
  const float* Wo   = (const float*)d_in[6];
  const float* ao1  = (const float*)d_in[7];
  const float* ao2  = (const float*)d_in[8];
  const float* W1   = (const float*)d_in[9];
  const float* b1   = (const float*)d_in[10];
  const float* pw   = (const float*)d_in[11];
  const float* W2   = (const float*)d_in[12];
  const float* b2   = (const float*)d_in[13];
  float* out = (float*)d_out;

  char* base = (char*)d_ws;
  size_t off = 0;
  auto alloc = [&](size_t bytes)->char*{
    char* p = base + off;
    off = (off + bytes + 255) & ~(size_t)255;
    return p;
  };
  unsigned long long* adjbits = (unsigned long long*)alloc((size_t)BB*NN*(NN/64)*8); // 2 MB
  int*   cnt1 = (int*)  alloc((size_t)BB*NN*4);
  _Float16* WhT  = (_Float16*)alloc((size_t)BB*NHEADS*NHID*NN*2);  // 4 MB, [bh][d][i]
  float* f1l  = (float*)alloc((size_t)BB*NHEADS*NN*4);
  float* f2l  = (float*)alloc((size_t)BB*NHEADS*NN*4);
  float* pc1  = (float*)alloc((size_t)2*BB*NN*(NHEADS*NHID)*4);    // 16 MB partial c (l1)
  float* pl1  = (float*)alloc((size_t)2*BB*NHEADS*NN*4);           // 256 KB partial l (l1)
  _Float16* WhT2 = (_Float16*)alloc((size_t)BB*NCLASS*NN*2);       // 512 KB, [b][d][i]
  float* f1ol = (float*)alloc((size_t)BB*NN*4);
  float* f2ol = (float*)alloc((size_t)BB*NN*4);
  float* pc   = (float*)alloc((size_t)256*1024*4);                 // 1 MB partial c (l2)
  float* pl   = (float*)alloc((size_t)256*32*4);                   // partial l (l2)

  float* pa = pc1;
  float* pb = pc1 + (size_t)BB*NN*(NHEADS*NHID);
  float* la = pl1;
  float* lb = pl1 + (size_t)BB*NHEADS*NN;

  prep<<<PROJ_BLOCKS + BB*NN, 512, 0, stream>>>(x, W, a1, a2, WhT, f1l, f2l,
                                                adj, adjbits, cnt1);
  attn_l1<<<BB*NHEADS*(NN/32)*2, 256, 0, stream>>>(adjbits, WhT, f1l, f2l, cnt1, pc1, pl1);
  out_proj2<<<BB*(NN/32), 256, 0, stream>>>(pa, pb, la, lb, Wo, ao1, ao2, WhT2, f1ol, f2ol);
  attn_l2<<<BB*8*8, 256, 0, stream>>>(adjbits, WhT2, f1ol, f2ol, cnt1, oh, pc, pl);
  classify2<<<(BB*KK1)/4, 256, 0, stream>>>(pc, pl, W1, b1, pw, W2, b2, out);
}

// Round 12
// 197.737 us; speedup vs baseline: 1.1599x; 1.1599x over previous
//
#include <hip/hip_runtime.h>
#include <hip/hip_bf16.h>
#include <stdint.h>
#include <math.h>

#define BB 4
#define NN 2048
#define NFEAT 256
#define NHID 64
#define NHEADS 4
#define NCLASS 32
#define KK1 256
#define ALPHA 0.2f
#define LOG2E 1.4426950408889634f

typedef _Float16 f16x8 __attribute__((ext_vector_type(8)));
typedef _Float16 f16x4 __attribute__((ext_vector_type(4)));
typedef _Float16 h16x2 __attribute__((ext_vector_type(2)));
typedef float f32x4 __attribute__((ext_vector_type(4)));

__device__ __forceinline__ f16x8 ld8(const _Float16* p){
  f16x8 r;
  *(f16x4*)&r = *(const f16x4*)p;
  *((f16x4*)&r + 1) = *(const f16x4*)(p + 4);
  return r;
}

__device__ __forceinline__ h16x2 pk2(float a, float b){
  auto v = __builtin_amdgcn_cvt_pkrtz(a, b);   // __fp16 x2
  h16x2 r;
  __builtin_memcpy(&r, &v, sizeof(r));
  return r;
}

__device__ __forceinline__ float fexp2(float x){
#if __has_builtin(__builtin_amdgcn_exp2f)
  return __builtin_amdgcn_exp2f(x);
#else
  return exp2f(x);
#endif
}

// ---------------- K0+K1 merged: pack_adj || wh_proj2 --------------------
// v13 = round-8 v9 verbatim (measured 203.7us total; prep 43.7us).
// pack_adj (memory-bound) and wh_proj2 (VALU-bound) share no data; one
// launch with grid concatenation hides packing traffic under projection
// FMA work and removes one launch/drain boundary. W addressing is
// wave-uniform (readfirstlane) => scalar s_load path (v10 lesson: per-lane
// dbase kills it, SGPR 96->32, 2x slower).
// Blocks [0,512): projection. Blocks [512,8704): adj packing.
__global__ void __launch_bounds__(256) prep(const float* __restrict__ x,
        const float* __restrict__ W, const float* __restrict__ a1, const float* __restrict__ a2,
        _Float16* __restrict__ whT, float* __restrict__ f1l, float* __restrict__ f2l,
        const int* __restrict__ adj, unsigned long long* __restrict__ bits,
        int* __restrict__ cnt){
  __shared__ __align__(16) float xs[64*65];
  __shared__ float red1[4][64];
  __shared__ float red2[4][64];
  __shared__ int csum[4];
  int tid = threadIdx.x;
  if (blockIdx.x >= BB*NHEADS*(NN/64)){
    // ---- pack_adj part ----
    int row = blockIdx.x - BB*NHEADS*(NN/64);   // b*N + i
    const int* arow = adj + (size_t)row * NN;
    int lane = tid & 63, wv = tid >> 6;
    int c = 0;
    #pragma unroll
    for (int it=0; it<NN/256; ++it){
      int j = it*256 + tid;
      unsigned long long m = __ballot(arow[j] > 0);
      if (lane==0){ bits[(size_t)row*(NN/64) + it*4 + wv] = m; c += __popcll(m); }
    }
    if (lane==0) csum[wv] = c;
    __syncthreads();
    if (tid==0) cnt[row] = csum[0]+csum[1]+csum[2]+csum[3];
    return;
  }
  // ---- wh_proj2 part (float2 accumulators for packed FMA) ----
  int bh = blockIdx.x >> 5;
  int i0 = (blockIdx.x & 31) * 64;
  int b = bh >> 2, h = bh & 3;
  int lane = tid & 63;
  int dbase = __builtin_amdgcn_readfirstlane(tid >> 6) * 16;
  float2 acc2[8];
  #pragma unroll
  for (int dd=0; dd<8; ++dd) acc2[dd] = float2{0.f, 0.f};
  for (int kc=0; kc<4; ++kc){
    int kb = kc*64;
    __syncthreads();
    #pragma unroll
    for (int t=0; t<4; ++t){
      int row = t*16 + (tid>>4);
      int f4 = (tid&15)*4;
      float4 v = *(const float4*)(x + ((size_t)(b*NN + i0 + row))*NFEAT + kb + f4);
      xs[row*65 + f4 + 0] = v.x;
      xs[row*65 + f4 + 1] = v.y;
      xs[row*65 + f4 + 2] = v.z;
      xs[row*65 + f4 + 3] = v.w;
    }
    __syncthreads();
    const float* Wb = W + (size_t)h*NFEAT*NHID + (size_t)kb*NHID + dbase;
    #pragma unroll 4
    for (int f=0; f<64; ++f){
      float xv = xs[lane*65 + f];
      const float2* wr2 = (const float2*)(Wb + (size_t)f*NHID);
      #pragma unroll
      for (int dd=0; dd<8; ++dd){
        acc2[dd].x = fmaf(xv, wr2[dd].x, acc2[dd].x);
        acc2[dd].y = fmaf(xv, wr2[dd].y, acc2[dd].y);
      }
    }
  }
  float p1 = 0.f, p2 = 0.f;
  #pragma unroll
  for (int dd=0; dd<16; ++dd){
    int d = dbase + dd;
    float a = (dd & 1) ? acc2[dd>>1].y : acc2[dd>>1].x;
    whT[((size_t)bh*NHID + d)*NN + i0 + lane] = (_Float16)a;
    p1 = fmaf(a, a1[h*NHID + d], p1);
    p2 = fmaf(a, a2[h*NHID + d], p2);
  }
  int wv = tid >> 6;
  red1[wv][lane] = p1;
  red2[wv][lane] = p2;
  __syncthreads();
  if (tid < 64){
    float s1 = red1[0][tid]+red1[1][tid]+red1[2][tid]+red1[3][tid];
    float s2 = red2[0][tid]+red2[1][tid]+red2[2][tid]+red2[3][tid];
    f1l[(size_t)bh*NN + i0 + tid] = s1 * LOG2E;
    f2l[(size_t)bh*NN + i0 + tid] = s2 * LOG2E;
  }
}

// ---------- K2: partial softmax(e) @ Wh, j-split x2, f16 MFMA -----------
// v7 structure (measured <40.2us): T14 async-STAGE register prefetch,
// exp2-in-loop weight path, AND-mask after exp2, grid 2048.
__global__ void __launch_bounds__(256) attn_l1(
        const unsigned long long* __restrict__ bits,
        const _Float16* __restrict__ whT,
        const float* __restrict__ f1l, const float* __restrict__ f2l,
        const int* __restrict__ cnt_in,
        float* __restrict__ pc, float* __restrict__ pl){
  const int JC = 128, PITCH = 132;
  __shared__ __align__(16) _Float16 whs[64*PITCH];   // 16.9 KB
  __shared__ __align__(16) _Float16 wts[32*PITCH];   // 8.4 KB
  int blk = blockIdx.x;
  int js = blk & 1;
  int tile = (blk >> 1) & 63;
  int bh = blk >> 7;
  int b = bh >> 2, h = bh & 3;
  int i0 = tile*32;
  int tid = threadIdx.x;
  int lane = tid & 63, wv = tid >> 6;
  int q = lane >> 4, col = lane & 15;
  int r = tid >> 3, jg = (tid & 7) * 16;
  float f1r = f1l[(size_t)bh*NN + i0 + r];
  bool czr = (cnt_in[b*NN + i0 + r] == 0);
  const unsigned short* mrow = (const unsigned short*)(bits + ((size_t)(b*NN + i0 + r))*(NN/64));
  const float* f2p = f2l + (size_t)bh*NN;
  const _Float16* whg = whT + (size_t)bh*NHID*NN;
  float lacc = 0.f;
  f32x4 c0 = {0.f,0.f,0.f,0.f}, c1 = {0.f,0.f,0.f,0.f};

  // register staging state (one j-chunk ahead)
  int sd0 = tid >> 4;            // staging row base (+16*dd)
  int sj8 = (tid & 15) * 8;      // staging j offset
  uint4 sreg[4];
  auto issue = [&](int it){
    #pragma unroll
    for (int dd=0; dd<4; ++dd)
      sreg[dd] = *(const uint4*)(whg + (size_t)(sd0 + dd*16)*NN + it*JC + sj8);
  };
  auto commit = [&](){
    #pragma unroll
    for (int dd=0; dd<4; ++dd){
      uint2* w2 = (uint2*)&whs[(sd0 + dd*16)*PITCH + sj8];
      w2[0] = uint2{sreg[dd].x, sreg[dd].y};
      w2[1] = uint2{sreg[dd].z, sreg[dd].w};
    }
  };

  issue(js*8);                   // prologue: first chunk (latency exposed once)
  for (int ii=0; ii<8; ++ii){
    int it = js*8 + ii;
    __syncthreads();             // whs free to overwrite
    commit();                    // ds_write from regs loaded last iter
    if (ii < 7) issue(it+1);     // prefetch next chunk; covered by rest of iter
    // weights: 32 rows x 128 j; 8 threads/row, 16 j each
    {
      unsigned int m16 = mrow[it*8 + (tid&7)];
      const float* fp = f2p + it*JC + jg;
      float4 fa = *(const float4*)(fp);
      float4 fb = *(const float4*)(fp+4);
      float4 fc = *(const float4*)(fp+8);
      float4 fd = *(const float4*)(fp+12);
      float fv[16] = {fa.x,fa.y,fa.z,fa.w, fb.x,fb.y,fb.z,fb.w,
                      fc.x,fc.y,fc.z,fc.w, fd.x,fd.y,fd.z,fd.w};
      h16x2 wp[8];
      #pragma unroll
      for (int p=0; p<8; ++p){
        float s0 = f1r + fv[2*p];
        float s1 = f1r + fv[2*p+1];
        float w0 = fexp2(fmaxf(s0, ALPHA*s0));
        float w1 = fexp2(fmaxf(s1, ALPHA*s1));
        // mask after exp2: masked lanes -> +0.0 (identical to exp2(-big))
        unsigned mb0 = (unsigned)(((int)(m16 << (31 - 2*p))) >> 31);
        unsigned mb1 = (unsigned)(((int)(m16 << (30 - 2*p))) >> 31);
        w0 = __uint_as_float(__float_as_uint(w0) & mb0);
        w1 = __uint_as_float(__float_as_uint(w1) & mb1);
        lacc += w0 + w1;
        wp[p] = pk2(w0, w1);
      }
      if (__builtin_expect(czr, 0)){
        h16x2 one2 = {(_Float16)1.f, (_Float16)1.f};
        #pragma unroll
        for (int p=0; p<8; ++p) wp[p] = one2;
      }
      uint2* wdst = (uint2*)&wts[r*PITCH + jg];
      const uint2* wsrc = (const uint2*)&wp[0];
      wdst[0]=wsrc[0]; wdst[1]=wsrc[1]; wdst[2]=wsrc[2]; wdst[3]=wsrc[3];
    }
    __syncthreads();
    // MFMA: wave wv = n-tile, 2 m-tiles, 4 k-steps
    #pragma unroll
    for (int ks=0; ks<4; ++ks){
      int kb = ks*32 + q*8;
      f16x8 a0 = ld8(&wts[col*PITCH + kb]);
      f16x8 a1v = ld8(&wts[(16+col)*PITCH + kb]);
      f16x8 bv = ld8(&whs[(wv*16+col)*PITCH + kb]);
      c0 = __builtin_amdgcn_mfma_f32_16x16x32_f16(a0, bv, c0, 0, 0, 0);
      c1 = __builtin_amdgcn_mfma_f32_16x16x32_f16(a1v, bv, c1, 0, 0, 0);
    }
  }
  lacc += __shfl_xor(lacc, 1, 64);
  lacc += __shfl_xor(lacc, 2, 64);
  lacc += __shfl_xor(lacc, 4, 64);
  float* plh = pl + (size_t)js*BB*NHEADS*NN;
  if ((tid & 7) == 0) plh[(size_t)bh*NN + i0 + r] = czr ? (float)(NN/2) : lacc;
  float* pch = pc + (size_t)js*BB*NN*(NHEADS*NHID);
  int dloc = wv*16 + col;
  #pragma unroll
  for (int mt=0; mt<2; ++mt){
    #pragma unroll
    for (int reg=0; reg<4; ++reg){
      int ir = mt*16 + q*4 + reg;
      pch[((size_t)(b*NN + i0 + ir))*(NHEADS*NHID) + h*NHID + dloc] =
          (mt==0 ? c0[reg] : c1[reg]);
    }
  }
}

// ---------------- K3a: fused combine + Wh2T = (h1 @ Wo)^T ---------------
// v8: 32 rows/block -> 256 blocks. Per-output math identical to v7.
__global__ void __launch_bounds__(256) out_proj2(const float* __restrict__ pa,
        const float* __restrict__ pb, const float* __restrict__ la, const float* __restrict__ lb,
        const float* __restrict__ Wo, const float* __restrict__ ao1, const float* __restrict__ ao2,
        _Float16* __restrict__ whT2, float* __restrict__ f1ol, float* __restrict__ f2ol){
  __shared__ __align__(16) float xs[32*65];    // 8.3 KB
  __shared__ float red1[8][32];
  __shared__ float red2[8][32];
  int b  = blockIdx.x >> 6;
  int i0 = (blockIdx.x & 63) * 32;
  int tid = threadIdx.x;
  int lane = tid & 63;
  int row_c = lane & 31;                        // compute row
  int grp = ((tid >> 6) << 1) | (lane >> 5);    // 0..7 col group
  int dbase = grp * 4;
  int row_s = tid >> 3;                         // staging row
  int f8 = (tid & 7) * 8;
  float acc[4] = {0.f,0.f,0.f,0.f};
  for (int kc=0; kc<4; ++kc){
    int kb = kc*64;
    __syncthreads();
    {
      int i = i0 + row_s;
      size_t lidx = ((size_t)(b*NHEADS + kc))*NN + i;
      float il = 1.f / (la[lidx] + lb[lidx]);
      size_t idx = ((size_t)(b*NN + i))*256 + kb + f8;
      float4 va0 = *(const float4*)(pa + idx);
      float4 va1 = *(const float4*)(pa + idx + 4);
      float4 vb0 = *(const float4*)(pb + idx);
      float4 vb1 = *(const float4*)(pb + idx + 4);
      float v[8] = {va0.x+vb0.x, va0.y+vb0.y, va0.z+vb0.z, va0.w+vb0.w,
                    va1.x+vb1.x, va1.y+vb1.y, va1.z+vb1.z, va1.w+vb1.w};
      #pragma unroll
      for (int k=0; k<8; ++k){
        float t2 = v[k]*il;
        xs[row_s*65 + f8 + k] = t2 > 0.f ? t2 : expm1f(t2);
      }
    }
    __syncthreads();
    #pragma unroll 4
    for (int f=0; f<64; ++f){
      float xv = xs[row_c*65 + f];
      float4 w4 = *(const float4*)(Wo + (size_t)(kb+f)*NCLASS + dbase);
      acc[0] = fmaf(xv, w4.x, acc[0]);
      acc[1] = fmaf(xv, w4.y, acc[1]);
      acc[2] = fmaf(xv, w4.z, acc[2]);
      acc[3] = fmaf(xv, w4.w, acc[3]);
    }
  }
  float p1 = 0.f, p2 = 0.f;
  #pragma unroll
  for (int dd=0; dd<4; ++dd){
    int d = dbase + dd;
    whT2[((size_t)b*NCLASS + d)*NN + i0 + row_c] = (_Float16)acc[dd];
    p1 = fmaf(acc[dd], ao1[d], p1);
    p2 = fmaf(acc[dd], ao2[d], p2);
  }
  red1[grp][row_c] = p1;
  red2[grp][row_c] = p2;
  __syncthreads();
  if (tid < 32){
    float s1 = 0.f, s2 = 0.f;
    #pragma unroll
    for (int g=0; g<8; ++g){ s1 += red1[g][tid]; s2 += red2[g][tid]; }
    f1ol[(size_t)b*NN + i0 + tid] = s1 * LOG2E;
    f2ol[(size_t)b*NN + i0 + tid] = s2 * LOG2E;
  }
}

// ---------- K3b: layer-2 attention, GATHERED rows only, j-split x8 ------
__global__ void __launch_bounds__(256) attn_l2(
        const unsigned long long* __restrict__ bits,
        const _Float16* __restrict__ whT2,
        const float* __restrict__ f1ol, const float* __restrict__ f2ol,
        const int* __restrict__ cnt_in, const int* __restrict__ oh,
        float* __restrict__ pc, float* __restrict__ pl){
  const int JC = 128, PITCH = 132;
  __shared__ __align__(16) _Float16 whs[32*PITCH];
  __shared__ __align__(16) _Float16 wts[32*PITCH];
  int blk = blockIdx.x;
  int js = blk & 7, kt = (blk>>3) & 7, b = blk >> 6;
  int tid = threadIdx.x;
  int lane = tid & 63, wv = tid >> 6;
  int q = lane >> 4, col = lane & 15;
  int r = tid >> 3, jg = (tid & 7) * 16;
  int row_i = oh[b*KK1 + kt*32 + r];
  float f1r = f1ol[b*NN + row_i];
  bool czr = (cnt_in[b*NN + row_i] == 0);
  const unsigned short* mrow = (const unsigned short*)(bits + ((size_t)(b*NN + row_i))*(NN/64));
  const float* f2p = f2ol + (size_t)b*NN;
  const _Float16* whg = whT2 + (size_t)b*NCLASS*NN;
  float lacc = 0.f;
  f32x4 c0 = {0.f,0.f,0.f,0.f};
  int mt = wv & 1, nt = wv >> 1;
  for (int ii=0; ii<2; ++ii){
    int it = js*2 + ii;
    __syncthreads();
    #pragma unroll
    for (int dd=0; dd<2; ++dd){
      int d = (tid>>4) + dd*16;
      int j8 = (tid&15)*8;
      uint4 v = *(const uint4*)(whg + (size_t)d*NN + it*JC + j8);
      uint2* w2 = (uint2*)&whs[d*PITCH + j8];
      w2[0] = uint2{v.x, v.y};
      w2[1] = uint2{v.z, v.w};
    }
    {
      unsigned int m16 = mrow[it*8 + (tid&7)];
      const float* fp = f2p + it*JC + jg;
      float4 fa = *(const float4*)(fp);
      float4 fb = *(const float4*)(fp+4);
      float4 fc = *(const float4*)(fp+8);
      float4 fd = *(const float4*)(fp+12);
      float fv[16] = {fa.x,fa.y,fa.z,fa.w, fb.x,fb.y,fb.z,fb.w,
                      fc.x,fc.y,fc.z,fc.w, fd.x,fd.y,fd.z,fd.w};
      h16x2 wp[8];
      #pragma unroll
      for (int p=0; p<8; ++p){
        float s0 = f1r + fv[2*p];
        float s1 = f1r + fv[2*p+1];
        s0 = (m16 & (1u<<(2*p)))   ? s0 : -1e5f;
        s1 = (m16 & (1u<<(2*p+1))) ? s1 : -1e5f;
        float e0 = fmaxf(s0, ALPHA*s0);
        float e1 = fmaxf(s1, ALPHA*s1);
        float w0 = exp2f(e0);
        float w1 = exp2f(e1);
        lacc += w0 + w1;
        wp[p] = pk2(w0, w1);
      }
      if (__builtin_expect(czr, 0)){
        h16x2 one2 = {(_Float16)1.f, (_Float16)1.f};
        #pragma unroll
        for (int p=0; p<8; ++p) wp[p] = one2;
        lacc += 16.f;
      }
      uint2* wdst = (uint2*)&wts[r*PITCH + jg];
      const uint2* wsrc = (const uint2*)&wp[0];
      wdst[0]=wsrc[0]; wdst[1]=wsrc[1]; wdst[2]=wsrc[2]; wdst[3]=wsrc[3];
    }
    __syncthreads();
    #pragma unroll
    for (int ks=0; ks<4; ++ks){
      int kb = ks*32 + q*8;
      f16x8 a0 = ld8(&wts[(mt*16+col)*PITCH + kb]);
      f16x8 bv = ld8(&whs[(nt*16+col)*PITCH + kb]);
      c0 = __builtin_amdgcn_mfma_f32_16x16x32_f16(a0, bv, c0, 0, 0, 0);
    }
  }
  lacc += __shfl_xor(lacc, 1, 64);
  lacc += __shfl_xor(lacc, 2, 64);
  lacc += __shfl_xor(lacc, 4, 64);
  if ((tid & 7) == 0) pl[blk*32 + r] = lacc;
  int dloc = nt*16 + col;
  #pragma unroll
  for (int reg=0; reg<4; ++reg){
    int ir = mt*16 + q*4 + reg;
    pc[(size_t)blk*1024 + ir*32 + dloc] = c0[reg];
  }
}

// ---------------- K4: combine partials + ELU + MLP ----------------------
__global__ void __launch_bounds__(256) classify2(const float* __restrict__ pc,
        const float* __restrict__ pl,
        const float* __restrict__ W1, const float* __restrict__ b1,
        const float* __restrict__ pw, const float* __restrict__ W2, const float* __restrict__ b2,
        float* __restrict__ out){
  __shared__ float efs[4][32];
  int wv = threadIdx.x >> 6;
  int lane = threadIdx.x & 63;
  int row = blockIdx.x*4 + wv;        // 0..B*K1-1
  int b = row >> 8, k = row & 255;
  int kt = k >> 5, r = k & 31;
  int base = (b*8 + kt)*8;
  if (lane < 32){
    float s = 0.f, l = 0.f;
    #pragma unroll
    for (int js=0; js<8; ++js){
      s += pc[(size_t)(base+js)*1024 + r*32 + lane];
      l += pl[(base+js)*32 + r];
    }
    float v = s / l;
    v = v > 0.f ? v : expm1f(v);
    efs[wv][lane] = v;
  }
  __syncthreads();
  const float* ef = efs[wv];
  int c = lane & 31;
  float y = b1[c];
  #pragma unroll 8
  for (int kk=0; kk<32; ++kk) y += ef[kk] * W1[kk*32 + c];
  y = y > 0.f ? y : pw[c]*y;
  float o0 = y * W2[c*2+0];
  float o1 = y * W2[c*2+1];
  #pragma unroll
  for (int o=16;o>0;o>>=1){ o0 += __shfl_xor(o0,o,64); o1 += __shfl_xor(o1,o,64); }
  if (lane==0){ out[row*2+0] = o0 + b2[0]; out[row*2+1] = o1 + b2[1]; }
}

extern "C" void kernel_launch(void* const* d_in, const int* in_sizes, int n_in,
                              void* d_out, int out_size, void* d_ws, size_t ws_size,
                              hipStream_t stream) {
  const float* x    = (const float*)d_in[0];
  const int*   adj  = (const int*)  d_in[1];
  const int*   oh   = (const int*)  d_in[2];
  const float* W    = (const float*)d_in[3];
  const float* a1   = (const float*)d_in[4];
  const float* a2   = (const float*)d_in[5];
  const float* Wo   = (const float*)d_in[6];
  const float* ao1  = (const float*)d_in[7];
  const float* ao2  = (const float*)d_in[8];
  const float* W1   = (const float*)d_in[9];
  const float* b1   = (const float*)d_in[10];
  const float* pw   = (const float*)d_in[11];
  const float* W2   = (const float*)d_in[12];
  const float* b2   = (const float*)d_in[13];
  float* out = (float*)d_out;

  char* base = (char*)d_ws;
  size_t off = 0;
  auto alloc = [&](size_t bytes)->char*{
    char* p = base + off;
    off = (off + bytes + 255) & ~(size_t)255;
    return p;
  };
  unsigned long long* adjbits = (unsigned long long*)alloc((size_t)BB*NN*(NN/64)*8); // 2 MB
  int*   cnt1 = (int*)  alloc((size_t)BB*NN*4);
  _Float16* WhT  = (_Float16*)alloc((size_t)BB*NHEADS*NHID*NN*2);  // 4 MB, [bh][d][i]
  float* f1l  = (float*)alloc((size_t)BB*NHEADS*NN*4);
  float* f2l  = (float*)alloc((size_t)BB*NHEADS*NN*4);
  float* pc1  = (float*)alloc((size_t)2*BB*NN*(NHEADS*NHID)*4);    // 16 MB partial c (l1)
  float* pl1  = (float*)alloc((size_t)2*BB*NHEADS*NN*4);           // 256 KB partial l (l1)
  _Float16* WhT2 = (_Float16*)alloc((size_t)BB*NCLASS*NN*2);       // 512 KB, [b][d][i]
  float* f1ol = (float*)alloc((size_t)BB*NN*4);
  float* f2ol = (float*)alloc((size_t)BB*NN*4);
  float* pc   = (float*)alloc((size_t)256*1024*4);                 // 1 MB partial c (l2)
  float* pl   = (float*)alloc((size_t)256*32*4);                   // partial l (l2)

  float* pa = pc1;
  float* pb = pc1 + (size_t)BB*NN*(NHEADS*NHID);
  float* la = pl1;
  float* lb = pl1 + (size_t)BB*NHEADS*NN;

  prep<<<BB*NHEADS*(NN/64) + BB*NN, 256, 0, stream>>>(x, W, a1, a2, WhT, f1l, f2l,
                                                      adj, adjbits, cnt1);
  attn_l1<<<BB*NHEADS*(NN/32)*2, 256, 0, stream>>>(adjbits, WhT, f1l, f2l, cnt1, pc1, pl1);
  out_proj2<<<BB*(NN/32), 256, 0, stream>>>(pa, pb, la, lb, Wo, ao1, ao2, WhT2, f1ol, f2ol);
  attn_l2<<<BB*8*8, 256, 0, stream>>>(adjbits, WhT2, f1ol, f2ol, cnt1, oh, pc, pl);
  classify2<<<(BB*KK1)/4, 256, 0, stream>>>(pc, pl, W1, b1, pw, W2, b2, out);
}